// Round 5
// baseline (37109.277 us; speedup 1.0000x reference)
//
#include <hip/hip_runtime.h>
#include <stdint.h>

// ---------------------------------------------------------------------------
// StabilizedNeuralODE v6: VGPR-resident w1/A + depth-3 rolling-ring stream.
//
// v5 (33.9 ms, PASSED) was stall-bound: 1060 cyc per 100-cyc stream
// iteration (depth-2 prefetch < glds completion latency under 32-deep per-CU
// DMA concurrency; plus full LDS round-trip for every weight byte).
// v6:
//  - w1 (16 B-frags) and A (4 B-frags) live in VGPRs for the whole kernel
//    (loaded once from a fragment-ordered static region). Phase A and the
//    A*y part of phase C consume no stream. Stream: 50 -> 40 groups/stage.
//  - Prefetch depth 3 (vmcnt(8), 12 glds in flight) through a 6-slot/wave
//    ring with rolling ring offset `ro` (+4096 mod 12288) and source offset
//    `igo` (+4096 mod 81920). Invariant (verified): read-iter m expects
//    source 4096m at ring 4096m mod 12288; issue-iter m-3 places exactly
//    that. Slot overwrite targets the pair secured in VGPRs by THIS iter's
//    lgkmcnt(0) (v5-verified fence order: VMW -> ds_read -> lgkm0 -> issue).
//  - Barriers stay raw s_barrier + lgkmcnt(0); vmcnt never drained in-loop.
//    s=5 out-stores only over-wait the counted vmcnt (in-order retirement).
//
// Structure: 32 WGs x 512 threads (8 waves, 2/SIMD); WG owns 16 batch rows.
// Stream order per wave (group g of 40, 2 KB each = 2 x 1 KB frag tiles):
//   g 0..31 : w2  (nt=(g&1)*2+tile, ks=g>>1)
//   g 32..39: w3  (kcol=2*(g-32)+tile)
// Static region per wave: w1 frags (idx 0..7: ks=idx>>1, nt=(idx&1)*2+tile),
//                         A frags (idx 8..9: kcol=2*(idx-8)+tile).
//
// MFMA 16x16x32_bf16 (verified): A-frag A[m=l16][k=quad*8+j],
// B-frag B[n=l16][k=quad*8+j], C/D n=l16, m=quad*4+reg.
// ---------------------------------------------------------------------------

#define Dd 128
#define Ww 512
#define Tt 512
#define NSTEP 511
#define NWG 32
#define NTHR 512

// workspace (ushort element offsets)
#define WSTR_W 40960            // stream: 40 groups x 1024 ush per wave
#define WSTAT_BASE 327680       // 8 * WSTR_W
#define WSTAT_W 10240           // static: 10 tiles x 1024 ush per wave
#define WS_TOT 409600           // 819,200 bytes

// LDS byte offsets
#define RING_W_B 12288          // 6 slots x 2048 B per wave
#define H1F 98304               // 16 x 512 bf16, fragment order (16 KB)
#define H2F 114688
#define Y0F 131072              // 16 x 128 bf16 frags (4 KB)
#define Y1F 135168
#define ATF 139264              // 6 x 8 f32 RK rows (192 B)
#define DTF 139520              // 511 f32 dt values
#define SMEMB 141568

typedef __attribute__((ext_vector_type(8))) __bf16 bf16x8;
typedef __attribute__((ext_vector_type(4))) float f32x4;

__device__ __forceinline__ unsigned short f2b(float f) {
  union { float f; unsigned int u; } v; v.f = f;
  return (unsigned short)((v.u + 0x7fffu + ((v.u >> 16) & 1u)) >> 16);
}
__device__ __forceinline__ float fast_tanh(float x) {
  x = fminf(fmaxf(x, -15.f), 15.f);
  float e = __expf(2.f * x);
  return (e - 1.f) / (e + 1.f);
}
// frag byte address of element (m=batch row 0..15, n=feature col):
// tile n>>5 (1 KB), lane ((n>>3)&3)*16+m (16 B), elem n&7.
__device__ __forceinline__ int fragaddr(int m, int n) {
  return ((n >> 5) << 10) + ((((n >> 3) & 3) * 16 + m) << 4) + ((n & 7) << 1);
}

// RK coefficients: rows 0..4 = A(s+1,*) zero-padded to 8, row 5 = B.
__device__ const float RKC[48] = {
  0.161f, 0.f, 0.f, 0.f, 0.f, 0.f, 0.f, 0.f,
  -0.008480655492356989f, 0.335480655492357f, 0.f, 0.f, 0.f, 0.f, 0.f, 0.f,
  2.8971530571054935f, -6.359448489975075f, 4.3622954328695815f, 0.f, 0.f, 0.f, 0.f, 0.f,
  5.325864828439257f, -11.748883564062828f, 7.4955393428898365f,
  -0.09249506636175525f, 0.f, 0.f, 0.f, 0.f,
  5.86145544294642f, -12.92096931784711f, 8.159367898576159f,
  -0.071584973281401f, -0.028269050394068383f, 0.f, 0.f, 0.f,
  0.09646076681806523f, 0.01f, 0.4798896504144996f, 1.379008574103742f,
  -3.290069515436081f, 2.324710524099774f, 0.f, 0.f
};

#define GLDS(gp, lp) __builtin_amdgcn_global_load_lds( \
    (const __attribute__((address_space(1))) unsigned int*)(const void*)(gp), \
    (__attribute__((address_space(3))) unsigned int*)(void*)(lp), 16, 0, 0)

// counted wait: completes this iter's 4 glds, leaves 8 (2 iters) in flight.
#define VMW8() do { asm volatile("s_waitcnt vmcnt(8)" ::: "memory"); \
                    __builtin_amdgcn_sched_barrier(0); } while (0)
// slot data provably in VGPRs before the overwrite issue
#define LGKM0() do { asm volatile("s_waitcnt lgkmcnt(0)" ::: "memory"); \
                     __builtin_amdgcn_sched_barrier(0); } while (0)
// barrier that does NOT drain vmcnt
#define LBAR() do { asm volatile("s_waitcnt lgkmcnt(0)" ::: "memory"); \
                    __builtin_amdgcn_s_barrier(); } while (0)

// issue one group pair (4 KB, 4 glds): ring dest ro_, stream source igo_
#define ISSUE4(ro_, igo_) do { \
    GLDS(gsb + (igo_),        ring_w + (ro_)); \
    GLDS(gsb + (igo_) + 1024, ring_w + (ro_) + 1024); \
    GLDS(gsb + (igo_) + 2048, ring_w + (ro_) + 2048); \
    GLDS(gsb + (igo_) + 3072, ring_w + (ro_) + 3072); } while (0)
#define ADV() do { ro  = (ro  == 8192)  ? 0 : ro  + 4096; \
                   igo = (igo == 77824) ? 0 : igo + 4096; } while (0)

#define MFMA(a, b, c) __builtin_amdgcn_mfma_f32_16x16x32_bf16((a), (b), (c), 0, 0, 0)
#define CPK(kd) do { kd[0]=kk[0]; kd[1]=kk[1]; kd[2]=kk[2]; kd[3]=kk[3]; } while (0)

// one-time permute+convert into workspace (stream + static, frag order)
__global__ void prep_kernel(const float* __restrict__ w1,
                            const float* __restrict__ w2,
                            const float* __restrict__ w3,
                            const float* __restrict__ Am,
                            unsigned short* __restrict__ wsb) {
  for (int i = blockIdx.x * blockDim.x + threadIdx.x; i < WS_TOT;
       i += gridDim.x * blockDim.x) {
    float v;
    if (i < WSTAT_BASE) {                       // stream region
      const int w = i / WSTR_W, r = i % WSTR_W;
      const int g = r >> 10, tile = (r >> 9) & 1;
      const int L = (r >> 3) & 63, j = r & 7;
      const int l16 = L & 15, q = L >> 4;
      if (g < 32) {
        const int nt = (g & 1) * 2 + tile, ks = g >> 1;
        v = w2[(w * 64 + nt * 16 + l16) * Ww + ks * 32 + q * 8 + j];
      } else {
        const int kcol = 2 * (g - 32) + tile;
        v = w3[(w * 16 + l16) * Ww + kcol * 32 + q * 8 + j];
      }
    } else {                                    // static region (w1, A)
      const int ii = i - WSTAT_BASE;
      const int w = ii / WSTAT_W, r = ii % WSTAT_W;
      const int idx = r >> 10, tile = (r >> 9) & 1;
      const int L = (r >> 3) & 63, j = r & 7;
      const int l16 = L & 15, q = L >> 4;
      if (idx < 8) {
        const int ks = idx >> 1, nt = (idx & 1) * 2 + tile;
        v = w1[(w * 64 + nt * 16 + l16) * Dd + ks * 32 + q * 8 + j];
      } else {
        const int kcol = 2 * (idx - 8) + tile;
        v = Am[(w * 16 + l16) * Dd + kcol * 32 + q * 8 + j];
      }
    }
    wsb[i] = f2b(v);
  }
}

__global__ void __launch_bounds__(NTHR, 1)
ode_kernel(const float* __restrict__ ts,
           const float* __restrict__ yi,
           const float* __restrict__ b1,
           const float* __restrict__ b2,
           const float* __restrict__ b3,
           float* __restrict__ out,
           const unsigned short* __restrict__ wsb)
{
  extern __shared__ char smem_c[];

  const int tid  = threadIdx.x;
  const int wid  = tid >> 6;
  const int lane = tid & 63;
  const int l16  = lane & 15;
  const int quad = lane >> 4;
  const int lob  = lane << 4;          // lane*16 bytes (LDS frag reads)
  const int b0   = blockIdx.x * 16;

  char* ring_w = smem_c + wid * RING_W_B;
  char* h1f = smem_c + H1F;
  char* h2f = smem_c + H2F;

  // per-wave stream source base (lane-linear within each 1 KB tile)
  const char* gsb = (const char*)(wsb + wid * WSTR_W) + (lane << 4);
  const unsigned short* wstat = wsb + WSTAT_BASE + wid * WSTAT_W;

  // ---- VGPR-resident w1 / A fragments (loaded once, coalesced) ----
  bf16x8 w1f[4][4];   // [ks][nt]
  #pragma unroll
  for (int ks = 0; ks < 4; ++ks)
    #pragma unroll
    for (int nt = 0; nt < 4; ++nt)
      w1f[ks][nt] = *(const bf16x8*)(wstat + (2*ks + (nt>>1)) * 1024 +
                                     (nt & 1) * 512 + (lane << 3));
  bf16x8 Af[4];       // [kcol]
  #pragma unroll
  for (int kc = 0; kc < 4; ++kc)
    Af[kc] = *(const bf16x8*)(wstat + 8192 + (kc>>1) * 1024 +
                              (kc & 1) * 512 + (lane << 3));

  // ---- one-time staging: RK table + dt into LDS; biases into regs ----
  if (tid < 48) *(float*)(smem_c + ATF + (tid << 2)) = RKC[tid];
  for (int i = tid; i < NSTEP; i += NTHR)
    *(float*)(smem_c + DTF + (i << 2)) = ts[i + 1] - ts[i];

  float b1v[4], b2v[4];
  #pragma unroll
  for (int nt = 0; nt < 4; ++nt) {
    b1v[nt] = b1[(wid << 6) + (nt << 4) + l16];
    b2v[nt] = b2[(wid << 6) + (nt << 4) + l16];
  }
  const float b3v = b3[(wid << 4) + l16];

  // h-frag write bases: n = wid*64+nt*16+l16, m = quad*4 (+r = r*16 B)
  int hwaddr[4];
  #pragma unroll
  for (int nt = 0; nt < 4; ++nt)
    hwaddr[nt] = fragaddr(quad << 2, (wid << 6) + (nt << 4) + l16);
  const int nC = (wid << 4) + l16;          // phase C/D column
  const int ydst = fragaddr(quad << 2, nC); // y-frag write base

  // ---- y0: 4 fp32 regs (rows quad*4+r, col nC), Y0F frags, out[t=0] ----
  float y[4];
  #pragma unroll
  for (int r = 0; r < 4; ++r) {
    y[r] = yi[(size_t)(b0 + (quad << 2) + r) * Dd + nC];
    *(unsigned short*)(smem_c + Y0F + ydst + (r << 4)) = f2b(y[r]);
    out[(size_t)(b0 + (quad << 2) + r) * (Tt * Dd) + nC] = y[r];
  }

  float k0[4] = {0,0,0,0}, k1[4] = {0,0,0,0}, k2[4] = {0,0,0,0},
        k3[4] = {0,0,0,0}, k4[4] = {0,0,0,0}, k5[4] = {0,0,0,0};

  __syncthreads();   // drains all init vmem

  // rolling ring/source offsets; prologue = 3 iterations in flight
  int ro = 0, igo = 12288;
  ISSUE4(0, 0); ISSUE4(4096, 4096); ISSUE4(8192, 8192);

  #pragma unroll 1
  for (int t = 0; t < NSTEP; ++t) {
    const float hdt = *(const float*)(smem_c + DTF + (t << 2));

    #pragma unroll 1
    for (int s = 0; s < 6; ++s) {
      const char* ybr = smem_c + ((s & 1) ? Y1F : Y0F);
      char*       ybw = smem_c + ((s & 1) ? Y0F : Y1F);

      LBAR();   // y(parity) ready; h buffers free

      // ---- phase A: h1 = tanh(a @ w1.T + b1); w1 from VGPRs -------------
      {
        f32x4 accA[4];
        #pragma unroll
        for (int nt = 0; nt < 4; ++nt) { f32x4 z = {0.f,0.f,0.f,0.f}; accA[nt] = z; }
        #pragma unroll
        for (int ks = 0; ks < 4; ++ks) {
          bf16x8 af = *(const bf16x8*)(ybr + (ks << 10) + lob);
          #pragma unroll
          for (int nt = 0; nt < 4; ++nt)
            accA[nt] = MFMA(af, w1f[ks][nt], accA[nt]);
        }
        #pragma unroll
        for (int nt = 0; nt < 4; ++nt)
          #pragma unroll
          for (int r = 0; r < 4; ++r)
            *(unsigned short*)(h1f + hwaddr[nt] + (r << 4)) =
                f2b(fast_tanh(accA[nt][r] + b1v[nt]));
      }
      LBAR();   // h1 ready

      // ---- phase B: h2 = tanh(h1 @ w2.T + b2); stream w2 (16 iters) -----
      {
        f32x4 accB[4];
        #pragma unroll
        for (int nt = 0; nt < 4; ++nt) { f32x4 z = {0.f,0.f,0.f,0.f}; accB[nt] = z; }
        #pragma unroll
        for (int ks = 0; ks < 16; ++ks) {
          VMW8();
          bf16x8 af = *(const bf16x8*)(h1f + (ks << 10) + lob);
          bf16x8 bv[4];
          #pragma unroll
          for (int nt = 0; nt < 4; ++nt)
            bv[nt] = *(const bf16x8*)(ring_w + ro + (nt << 10) + lob);
          LGKM0();
          ISSUE4(ro, igo);
          ADV();
          #pragma unroll
          for (int nt = 0; nt < 4; ++nt)
            accB[nt] = MFMA(af, bv[nt], accB[nt]);
        }
        #pragma unroll
        for (int nt = 0; nt < 4; ++nt)
          #pragma unroll
          for (int r = 0; r < 4; ++r)
            *(unsigned short*)(h2f + hwaddr[nt] + (r << 4)) =
                f2b(fast_tanh(accB[nt][r] + b2v[nt]));
      }
      LBAR();   // h2 ready

      // ---- phase C: k = h2 @ w3.T + b3 + a @ A.T; stream w3 (4 iters) ---
      {
        f32x4 accC0 = {0.f, 0.f, 0.f, 0.f};
        f32x4 accC1 = {0.f, 0.f, 0.f, 0.f};
        #pragma unroll
        for (int cc = 0; cc < 4; ++cc) {
          VMW8();
          bf16x8 afv[4], bv[4];
          #pragma unroll
          for (int t4 = 0; t4 < 4; ++t4) {
            afv[t4] = *(const bf16x8*)(h2f + ((4*cc + t4) << 10) + lob);
            bv[t4]  = *(const bf16x8*)(ring_w + ro + (t4 << 10) + lob);
          }
          LGKM0();
          ISSUE4(ro, igo);
          ADV();
          accC0 = MFMA(afv[0], bv[0], accC0);
          accC1 = MFMA(afv[1], bv[1], accC1);
          accC0 = MFMA(afv[2], bv[2], accC0);
          accC1 = MFMA(afv[3], bv[3], accC1);
        }
        // A * y from VGPR-resident Af
        #pragma unroll
        for (int kc = 0; kc < 4; ++kc) {
          bf16x8 afy = *(const bf16x8*)(ybr + (kc << 10) + lob);
          if (kc & 1) accC1 = MFMA(afy, Af[kc], accC1);
          else        accC0 = MFMA(afy, Af[kc], accC0);
        }
        float kk[4];
        #pragma unroll
        for (int r = 0; r < 4; ++r) kk[r] = accC0[r] + accC1[r] + b3v;
        switch (s) {
          case 0: CPK(k0); break;
          case 1: CPK(k1); break;
          case 2: CPK(k2); break;
          case 3: CPK(k3); break;
          case 4: CPK(k4); break;
          default: CPK(k5); break;
        }
      }

      // ---- phase D: RK combine in registers; write y-stage frags --------
      {
        const float* cp = (const float*)(smem_c + ATF + (s << 5));
        const float c0 = cp[0], c1 = cp[1], c2 = cp[2];
        const float c3 = cp[3], c4 = cp[4], c5 = cp[5];
        float a_[4];
        #pragma unroll
        for (int r = 0; r < 4; ++r)
          a_[r] = y[r] + hdt * (c0*k0[r] + c1*k1[r] + c2*k2[r] +
                                c3*k3[r] + c4*k4[r] + c5*k5[r]);
        #pragma unroll
        for (int r = 0; r < 4; ++r)
          *(unsigned short*)(ybw + ydst + (r << 4)) = f2b(a_[r]);
        if (s == 5) {
          #pragma unroll
          for (int r = 0; r < 4; ++r) {
            y[r] = a_[r];
            out[(size_t)(b0 + (quad << 2) + r) * (Tt * Dd) +
                (size_t)(t + 1) * Dd + nC] = a_[r];
          }
        }
      }
    } // stages
  } // steps
}

extern "C" void kernel_launch(void* const* d_in, const int* in_sizes, int n_in,
                              void* d_out, int out_size, void* d_ws, size_t ws_size,
                              hipStream_t stream) {
  (void)in_sizes; (void)n_in; (void)out_size; (void)ws_size;

  const float* ts = (const float*)d_in[0];
  const float* yi = (const float*)d_in[1];
  const float* w1 = (const float*)d_in[2];
  const float* b1 = (const float*)d_in[3];
  const float* w2 = (const float*)d_in[4];
  const float* b2 = (const float*)d_in[5];
  const float* w3 = (const float*)d_in[6];
  const float* b3 = (const float*)d_in[7];
  const float* Am = (const float*)d_in[8];
  float* outp = (float*)d_out;
  unsigned short* wsb = (unsigned short*)d_ws;

  (void)hipFuncSetAttribute(reinterpret_cast<const void*>(ode_kernel),
                            hipFuncAttributeMaxDynamicSharedMemorySize,
                            SMEMB);

  prep_kernel<<<400, 256, 0, stream>>>(w1, w2, w3, Am, wsb);
  ode_kernel<<<dim3(NWG), dim3(NTHR), SMEMB, stream>>>(
      ts, yi, b1, b2, b3, outp, wsb);
}